// Round 8
// baseline (127.630 us; speedup 1.0000x reference)
//
#include <hip/hip_runtime.h>
#include <stdint.h>

#define Bn 2
#define Tn 2048
#define Cn 1024
#define Hn 16
#define Dn 64
#define Mn (Bn*Tn)

typedef __attribute__((ext_vector_type(8))) short bf16x8;
typedef __attribute__((ext_vector_type(4))) float f32x4;
typedef __attribute__((ext_vector_type(16))) float f32x16;
typedef __attribute__((ext_vector_type(4))) unsigned int u32x4;
typedef __attribute__((ext_vector_type(2))) unsigned int u32x2;
typedef unsigned short u16;

__device__ __forceinline__ u16 f2bf(float f) {
  union { float f; uint32_t u; } v; v.f = f;
  uint32_t u = v.u;
  return (u16)((u + 0x7fffu + ((u >> 16) & 1u)) >> 16);
}

__device__ __forceinline__ uint32_t pk_bf16(float lo, float hi) {
  uint32_t r;
  asm volatile("v_cvt_pk_bf16_f32 %0, %1, %2" : "=v"(r) : "v"(lo), "v"(hi));
  return r;
}

__device__ __forceinline__ void async16(const void* g, void* lds) {
  __builtin_amdgcn_global_load_lds((const __attribute__((address_space(1))) void*)g,
                                   (__attribute__((address_space(3))) void*)lds,
                                   16, 0, 0);
}

// ---------------- conversion kernels ----------------

__global__ void cvt_x(const float* __restrict__ x, u16* __restrict__ xb) {
  int i = (blockIdx.x * 256 + threadIdx.x) * 4;
  float4 v = *(const float4*)(x + i);
  ushort4 o;
  o.x = f2bf(v.x); o.y = f2bf(v.y); o.z = f2bf(v.z); o.w = f2bf(v.w);
  *(ushort4*)(xb + i) = o;
}

// in: [K][N] f32 row-major  ->  out: [N][K] bf16 row-major (transpose + convert)
template<int K, int N>
__global__ void cvt_T(const float* __restrict__ in, u16* __restrict__ out) {
  __shared__ float tile[32][33];
  int n0 = blockIdx.x * 32, k0 = blockIdx.y * 32;
  int tx = threadIdx.x & 31, ty = threadIdx.x >> 5;  // 32 x 8
  #pragma unroll
  for (int i = 0; i < 32; i += 8)
    tile[ty + i][tx] = in[(size_t)(k0 + ty + i) * N + n0 + tx];
  __syncthreads();
  #pragma unroll
  for (int i = 0; i < 32; i += 8)
    out[(size_t)(n0 + ty + i) * K + k0 + tx] = f2bf(tile[tx][ty + i]);
}

// ---------------- GEMM:  C[M,N] = A[M,K=1024] * Bt[N,K]^T  (bf16 in, f32 acc) ----------------

template<int EPI>
__launch_bounds__(256, 3)
__global__ void gemm_bt(const u16* __restrict__ A, const u16* __restrict__ Bt, int N,
                        u16* __restrict__ Qb, u16* __restrict__ Kb, u16* __restrict__ Vb,
                        float* __restrict__ Out, const float* __restrict__ bias) {
  constexpr int Kd = 1024;
  __shared__ u16 As[128][64];
  __shared__ u16 Bs[128][64];
  const int nT = N >> 7;
  const int cpx = gridDim.x >> 3;
  const int wg = (blockIdx.x & 7) * cpx + (blockIdx.x >> 3);   // XCD-chunked
  const int m0 = (wg / nT) << 7;
  const int n0 = (wg % nT) << 7;
  const int tid = threadIdx.x;
  const int lane = tid & 63, wid = tid >> 6;
  const int wr = wid >> 1, wc = wid & 1;
  const int lr = lane & 15, lg = lane >> 4;

  f32x4 acc[4][4] = {};

  for (int kb = 0; kb < Kd; kb += 64) {
    #pragma unroll
    for (int i = 0; i < 4; ++i) {
      int c = (wid * 4 + i) * 64 + lane;     // chunk id 0..1023
      int row = c >> 3, ko = (c & 7) << 3;
      async16(A + (size_t)(m0 + row) * Kd + kb + ko, &As[0][0] + c * 8);
      async16(Bt + (size_t)(n0 + row) * Kd + kb + ko, &Bs[0][0] + c * 8);
    }
    __syncthreads();
    bf16x8 af[2][4], bf[2][4];
    #pragma unroll
    for (int kc = 0; kc < 2; ++kc) {
      #pragma unroll
      for (int mi = 0; mi < 4; ++mi) {
        af[kc][mi] = *(const bf16x8*)&As[wr * 64 + mi * 16 + lr][kc * 32 + lg * 8];
        bf[kc][mi] = *(const bf16x8*)&Bs[wc * 64 + mi * 16 + lr][kc * 32 + lg * 8];
      }
    }
    #pragma unroll
    for (int kc = 0; kc < 2; ++kc)
      #pragma unroll
      for (int mi = 0; mi < 4; ++mi)
        #pragma unroll
        for (int ni = 0; ni < 4; ++ni)
          acc[mi][ni] = __builtin_amdgcn_mfma_f32_16x16x32_bf16(af[kc][mi], bf[kc][ni], acc[mi][ni], 0, 0, 0);
    __syncthreads();
  }

  if constexpr (EPI == 0) {
    #pragma unroll
    for (int mi = 0; mi < 4; ++mi) {
      int r0 = m0 + wr * 64 + mi * 16 + lg * 4;   // 4 consecutive rows
      int bb = r0 >> 11;
      int t0 = r0 & 2047;
      #pragma unroll
      for (int ni = 0; ni < 4; ++ni) {
        int col = n0 + wc * 64 + ni * 16 + lr;
        int sel = col >> 10, rem = col & 1023;
        int h = rem >> 6, d = rem & 63;
        f32x4 v = acc[mi][ni];
        if (sel == 0) {
          size_t base = ((size_t)(bb * Hn + h) * Tn + t0) * Dn + d;
          #pragma unroll
          for (int r = 0; r < 4; ++r) Qb[base + (size_t)r * Dn] = f2bf(v[r] * 0.125f);
        } else if (sel == 1) {
          size_t base = ((size_t)(bb * Hn + h) * Tn + t0) * Dn + d;
          #pragma unroll
          for (int r = 0; r < 4; ++r) Kb[base + (size_t)r * Dn] = f2bf(v[r]);
        } else {
          size_t base = ((size_t)(bb * Hn + h) * Dn + d) * Tn + t0;
          ushort4 o;
          o.x = f2bf(v[0]); o.y = f2bf(v[1]); o.z = f2bf(v[2]); o.w = f2bf(v[3]);
          *(ushort4*)(Vb + base) = o;
        }
      }
    }
  } else {
    #pragma unroll
    for (int mi = 0; mi < 4; ++mi) {
      int r0 = m0 + wr * 64 + mi * 16 + lg * 4;
      #pragma unroll
      for (int ni = 0; ni < 4; ++ni) {
        int col = n0 + wc * 64 + ni * 16 + lr;
        float bv = bias[col];
        #pragma unroll
        for (int r = 0; r < 4; ++r)
          Out[(size_t)(r0 + r) * Cn + col] = acc[mi][ni][r] + bv;
      }
    }
  }
}

// ---------------- flash attention v6: 32x32 MFMA, in-register P ----------------
// grid: 512 = 8 XCD x (4 bh-local x 16 q-tiles of 128 rows, longest first).
// 4 waves x 32 q-rows. K,V double-buffered in LDS (same staging as v4/v5).
// S^T = mfma32(K,Q): lane holds S[k = ksub*32 + (g&3)+8*(g>>2)+4*hi][q = lane&31].
// P repacked in-register via cvt_pk + shfl_xor(32) (partner lane^32 holds the
// other half of each depth-16 chain). O^T = mfma32(V^T, P), transposed out
// through a swizzled LDS scratch aliasing Ks.

__device__ __forceinline__ void stage_kv(const u16* __restrict__ K,
                                         const u16* __restrict__ Vt, int k0,
                                         u16* __restrict__ Kbuf, u16* __restrict__ Vbuf,
                                         int tid) {
  #pragma unroll
  for (int i = 0; i < 2; ++i) {
    int c = i * 256 + tid;            // chunk 0..511 (16 B each)
    int row = c >> 3;
    int js = (c & 7) ^ (row & 7);     // inverse-swizzled source chunk
    async16(K + (size_t)(k0 + row) * Dn + js * 8, Kbuf + c * 8);
    async16(Vt + (size_t)row * Tn + k0 + js * 8, Vbuf + c * 8);
  }
}

__launch_bounds__(256, 3)
__global__ void attn(const u16* __restrict__ Qb, const u16* __restrict__ Kb,
                     const u16* __restrict__ Vb, u16* __restrict__ Ob) {
  __shared__ u16 __attribute__((aligned(16))) Ks[2 * 4096];
  __shared__ u16 __attribute__((aligned(16))) Vs[2 * 4096];

  const int raw = blockIdx.x;
  const int xcd = raw & 7;
  const int idx = raw >> 3;                 // 0..63
  const int bh  = xcd * 4 + (idx & 3);      // 4 heads per XCD
  const int qt  = 15 - (idx >> 2);          // longest q-tiles first
  const int q0  = qt * 128;
  const int nt  = 2 * qt + 2;

  const int tid = threadIdx.x;
  const int lane = tid & 63, wid = tid >> 6;
  const int l31 = lane & 31, hi = lane >> 5;
  const int bb = bh >> 4, h = bh & 15;

  const u16* Q  = Qb + (size_t)bh * Tn * Dn;
  const u16* K  = Kb + (size_t)bh * Tn * Dn;
  const u16* Vt = Vb + (size_t)bh * Dn * Tn;

  const int swz = lane & 7;                 // read-side XOR key (row&7 == lane&7)
  const int qg = q0 + wid * 32 + l31;       // this lane's q row

  // Q fragments (B operand): qf[c] = Q[qg][c*16 + hi*8 .. +7]
  bf16x8 qf[4];
  #pragma unroll
  for (int c = 0; c < 4; ++c)
    qf[c] = *(const bf16x8*)(Q + (size_t)qg * Dn + c * 16 + hi * 8);

  f32x16 o0 = {}, o1 = {};                  // O^T rows d = sub*32 + (g&3)+8*(g>>2)+4*hi
  float m = -1e30f, den = 0.f;

  int cur = 0;
  stage_kv(K, Vt, 0, Ks, Vs, tid);
  __syncthreads();

  for (int t = 0; t < nt; ++t) {
    const int k0 = t << 6;
    if (t + 1 < nt)
      stage_kv(K, Vt, (t + 1) << 6,
               Ks + (cur ^ 1) * 4096, Vs + (cur ^ 1) * 4096, tid);

    const u16* Kc = Ks + cur * 4096;
    const u16* Vc = Vs + cur * 4096;

    // S^T = K Q^T
    f32x16 s0 = {}, s1 = {};
    __builtin_amdgcn_s_setprio(1);
    #pragma unroll
    for (int c = 0; c < 4; ++c) {
      bf16x8 kf0 = *(const bf16x8*)(Kc + l31 * 64 + (((c * 2 + hi) ^ swz) * 8));
      bf16x8 kf1 = *(const bf16x8*)(Kc + (32 + l31) * 64 + (((c * 2 + hi) ^ swz) * 8));
      s0 = __builtin_amdgcn_mfma_f32_32x32x16_bf16(kf0, qf[c], s0, 0, 0, 0);
      s1 = __builtin_amdgcn_mfma_f32_32x32x16_bf16(kf1, qf[c], s1, 0, 0, 0);
    }
    __builtin_amdgcn_s_setprio(0);

    if (t >= nt - 2) {                      // diagonal tiles: mask k > q
      #pragma unroll
      for (int g = 0; g < 16; ++g) {
        int kl = (g & 3) + 8 * (g >> 2) + 4 * hi;
        if (k0 + kl > qg)      s0[g] = -1e30f;
        if (k0 + 32 + kl > qg) s1[g] = -1e30f;
      }
    }

    // row max: 31 in-lane + 1 cross-half shuffle
    float pm = s0[0];
    #pragma unroll
    for (int g = 1; g < 16; ++g) pm = fmaxf(pm, s0[g]);
    #pragma unroll
    for (int g = 0; g < 16; ++g) pm = fmaxf(pm, s1[g]);
    pm = fmaxf(pm, __shfl_xor(pm, 32));

    // defer-max (THR=8)
    if (!__all(pm - m <= 8.f)) {
      float mn = fmaxf(m, pm);
      float fac = __expf(m - mn);
      den *= fac;
      #pragma unroll
      for (int g = 0; g < 16; ++g) { o0[g] *= fac; o1[g] *= fac; }
      m = mn;
    }

    float sum = 0.f;
    #pragma unroll
    for (int g = 0; g < 16; ++g) { float p = __expf(s0[g] - m); s0[g] = p; sum += p; }
    #pragma unroll
    for (int g = 0; g < 16; ++g) { float p = __expf(s1[g] - m); s1[g] = p; sum += p; }
    sum += __shfl_xor(sum, 32);
    den += sum;

    // repack P in-register: per depth-16 chain, partner lane^32 holds the
    // missing half. R0=hi?wsw:u  R1=hi?zsw:v  R2=hi?w:usw  R3=hi?z:vsw
    bf16x8 pfrag[4];
    #define MKFRAG(SV, C2, OUT) { \
      uint32_t u_ = pk_bf16(SV[8*(C2)+0], SV[8*(C2)+1]); \
      uint32_t v_ = pk_bf16(SV[8*(C2)+2], SV[8*(C2)+3]); \
      uint32_t w_ = pk_bf16(SV[8*(C2)+4], SV[8*(C2)+5]); \
      uint32_t z_ = pk_bf16(SV[8*(C2)+6], SV[8*(C2)+7]); \
      uint32_t us = __shfl_xor(u_, 32), vs = __shfl_xor(v_, 32); \
      uint32_t ws = __shfl_xor(w_, 32), zs = __shfl_xor(z_, 32); \
      u32x4 q4; \
      q4.x = hi ? ws : u_; q4.y = hi ? zs : v_; \
      q4.z = hi ? w_ : us; q4.w = hi ? z_ : vs; \
      OUT = __builtin_bit_cast(bf16x8, q4); }
    MKFRAG(s0, 0, pfrag[0]); MKFRAG(s0, 1, pfrag[1]);
    MKFRAG(s1, 0, pfrag[2]); MKFRAG(s1, 1, pfrag[3]);
    #undef MKFRAG

    // O^T += V^T P
    __builtin_amdgcn_s_setprio(1);
    #pragma unroll
    for (int kc = 0; kc < 4; ++kc) {
      bf16x8 vf0 = *(const bf16x8*)(Vc + l31 * 64 + (((kc * 2 + hi) ^ swz) * 8));
      bf16x8 vf1 = *(const bf16x8*)(Vc + (32 + l31) * 64 + (((kc * 2 + hi) ^ swz) * 8));
      o0 = __builtin_amdgcn_mfma_f32_32x32x16_bf16(vf0, pfrag[kc], o0, 0, 0, 0);
      o1 = __builtin_amdgcn_mfma_f32_32x32x16_bf16(vf1, pfrag[kc], o1, 0, 0, 0);
    }
    __builtin_amdgcn_s_setprio(0);

    __syncthreads();                 // drains vmcnt (stage t+1) + LDS reads done
    cur ^= 1;
  }

  // ---- epilogue: normalize, transpose O^T -> O rows via swizzled LDS ----
  float inv = 1.f / den;
  uint32_t* Owv = (uint32_t*)Ks + (wid << 10);   // per-wave 4KB: [32 q][32 u32 slots]
  #pragma unroll
  for (int e = 0; e < 16; e += 2) {
    uint32_t p0 = pk_bf16(o0[e] * inv, o0[e + 1] * inv);
    uint32_t p1 = pk_bf16(o1[e] * inv, o1[e + 1] * inv);
    int sl0 = ((e & 3) >> 1) + ((e >> 2) << 2) + (hi << 1);   // d/2 slot, dsub 0
    int sl1 = sl0 + 16;                                       // dsub 1
    Owv[(l31 << 5) + (((sl0 >> 2) ^ (l31 & 7)) << 2) + (sl0 & 3)] = p0;
    Owv[(l31 << 5) + (((sl1 >> 2) ^ (l31 & 7)) << 2) + (sl1 & 3)] = p1;
  }
  __syncthreads();
  u16* obase = Ob + ((size_t)(bb * Tn + q0 + wid * 32 + l31)) * Cn + h * Dn;
  #pragma unroll
  for (int i = 0; i < 4; ++i) {
    int c = (hi << 2) + i;                                    // 16B chunk = 8 d-values
    u32x4 vv = *(const u32x4*)&Owv[(l31 << 5) + ((c ^ (l31 & 7)) << 2)];
    *(u32x4*)(obase + c * 8) = vv;
  }
}

// ---------------- launch ----------------

extern "C" void kernel_launch(void* const* d_in, const int* in_sizes, int n_in,
                              void* d_out, int out_size, void* d_ws, size_t ws_size,
                              hipStream_t stream) {
  const float* x = (const float*)d_in[0];
  const float* w_qkv = (const float*)d_in[1];
  const float* w_proj = (const float*)d_in[2];
  const float* b_proj = (const float*)d_in[3];
  float* out = (float*)d_out;
  char* ws = (char*)d_ws;

  u16* xb     = (u16*)(ws);                       // 8 MB (reused as attn_out after gemm1)
  u16* wqkvT  = (u16*)(ws + (size_t)( 8u << 20)); // 6 MB
  u16* wprojT = (u16*)(ws + (size_t)(14u << 20)); // 2 MB
  u16* Qb     = (u16*)(ws + (size_t)(16u << 20)); // 8 MB
  u16* Kb     = (u16*)(ws + (size_t)(24u << 20)); // 8 MB
  u16* Vb     = (u16*)(ws + (size_t)(32u << 20)); // 8 MB  (total 40 MB)

  cvt_x<<<dim3(4096), dim3(256), 0, stream>>>(x, xb);
  cvt_T<1024, 3072><<<dim3(96, 32), dim3(256), 0, stream>>>(w_qkv, wqkvT);
  cvt_T<1024, 1024><<<dim3(32, 32), dim3(256), 0, stream>>>(w_proj, wprojT);

  gemm_bt<0><<<dim3(32 * 24), dim3(256), 0, stream>>>(xb, wqkvT, 3072,
                                                      Qb, Kb, Vb, nullptr, nullptr);
  attn<<<dim3(512), dim3(256), 0, stream>>>(Qb, Kb, Vb, xb /* attn_out */);
  gemm_bt<1><<<dim3(32 * 8), dim3(256), 0, stream>>>(xb, wprojT, 1024,
                                                     nullptr, nullptr, nullptr, out, b_proj);
}

// Round 9
// 127.630 us; speedup vs baseline: 1.0000x; 1.0000x over previous
//
#include <hip/hip_runtime.h>
#include <stdint.h>

#define Bn 2
#define Tn 2048
#define Cn 1024
#define Hn 16
#define Dn 64
#define Mn (Bn*Tn)

typedef __attribute__((ext_vector_type(8))) short bf16x8;
typedef __attribute__((ext_vector_type(4))) float f32x4;
typedef __attribute__((ext_vector_type(16))) float f32x16;
typedef __attribute__((ext_vector_type(4))) unsigned int u32x4;
typedef __attribute__((ext_vector_type(2))) unsigned int u32x2;
typedef unsigned short u16;

__device__ __forceinline__ u16 f2bf(float f) {
  union { float f; uint32_t u; } v; v.f = f;
  uint32_t u = v.u;
  return (u16)((u + 0x7fffu + ((u >> 16) & 1u)) >> 16);
}

__device__ __forceinline__ uint32_t pk_bf16(float lo, float hi) {
  uint32_t r;
  asm volatile("v_cvt_pk_bf16_f32 %0, %1, %2" : "=v"(r) : "v"(lo), "v"(hi));
  return r;
}

__device__ __forceinline__ void async16(const void* g, void* lds) {
  __builtin_amdgcn_global_load_lds((const __attribute__((address_space(1))) void*)g,
                                   (__attribute__((address_space(3))) void*)lds,
                                   16, 0, 0);
}

// ---------------- conversion kernels ----------------

__global__ void cvt_x(const float* __restrict__ x, u16* __restrict__ xb) {
  int i = (blockIdx.x * 256 + threadIdx.x) * 4;
  float4 v = *(const float4*)(x + i);
  ushort4 o;
  o.x = f2bf(v.x); o.y = f2bf(v.y); o.z = f2bf(v.z); o.w = f2bf(v.w);
  *(ushort4*)(xb + i) = o;
}

// in: [K][N] f32 row-major  ->  out: [N][K] bf16 row-major (transpose + convert)
template<int K, int N>
__global__ void cvt_T(const float* __restrict__ in, u16* __restrict__ out) {
  __shared__ float tile[32][33];
  int n0 = blockIdx.x * 32, k0 = blockIdx.y * 32;
  int tx = threadIdx.x & 31, ty = threadIdx.x >> 5;  // 32 x 8
  #pragma unroll
  for (int i = 0; i < 32; i += 8)
    tile[ty + i][tx] = in[(size_t)(k0 + ty + i) * N + n0 + tx];
  __syncthreads();
  #pragma unroll
  for (int i = 0; i < 32; i += 8)
    out[(size_t)(n0 + ty + i) * K + k0 + tx] = f2bf(tile[tx][ty + i]);
}

// ---------------- GEMM:  C[M,N] = A[M,K=1024] * Bt[N,K]^T  (bf16 in, f32 acc) ----------------

template<int EPI>
__launch_bounds__(256, 3)
__global__ void gemm_bt(const u16* __restrict__ A, const u16* __restrict__ Bt, int N,
                        u16* __restrict__ Qb, u16* __restrict__ Kb, u16* __restrict__ Vb,
                        float* __restrict__ Out, const float* __restrict__ bias) {
  constexpr int Kd = 1024;
  __shared__ u16 As[128][64];
  __shared__ u16 Bs[128][64];
  const int nT = N >> 7;
  const int cpx = gridDim.x >> 3;
  const int wg = (blockIdx.x & 7) * cpx + (blockIdx.x >> 3);   // XCD-chunked
  const int m0 = (wg / nT) << 7;
  const int n0 = (wg % nT) << 7;
  const int tid = threadIdx.x;
  const int lane = tid & 63, wid = tid >> 6;
  const int wr = wid >> 1, wc = wid & 1;
  const int lr = lane & 15, lg = lane >> 4;

  f32x4 acc[4][4] = {};

  for (int kb = 0; kb < Kd; kb += 64) {
    #pragma unroll
    for (int i = 0; i < 4; ++i) {
      int c = (wid * 4 + i) * 64 + lane;     // chunk id 0..1023
      int row = c >> 3, ko = (c & 7) << 3;
      async16(A + (size_t)(m0 + row) * Kd + kb + ko, &As[0][0] + c * 8);
      async16(Bt + (size_t)(n0 + row) * Kd + kb + ko, &Bs[0][0] + c * 8);
    }
    __syncthreads();
    bf16x8 af[2][4], bf[2][4];
    #pragma unroll
    for (int kc = 0; kc < 2; ++kc) {
      #pragma unroll
      for (int mi = 0; mi < 4; ++mi) {
        af[kc][mi] = *(const bf16x8*)&As[wr * 64 + mi * 16 + lr][kc * 32 + lg * 8];
        bf[kc][mi] = *(const bf16x8*)&Bs[wc * 64 + mi * 16 + lr][kc * 32 + lg * 8];
      }
    }
    #pragma unroll
    for (int kc = 0; kc < 2; ++kc)
      #pragma unroll
      for (int mi = 0; mi < 4; ++mi)
        #pragma unroll
        for (int ni = 0; ni < 4; ++ni)
          acc[mi][ni] = __builtin_amdgcn_mfma_f32_16x16x32_bf16(af[kc][mi], bf[kc][ni], acc[mi][ni], 0, 0, 0);
    __syncthreads();
  }

  if constexpr (EPI == 0) {
    #pragma unroll
    for (int mi = 0; mi < 4; ++mi) {
      int r0 = m0 + wr * 64 + mi * 16 + lg * 4;   // 4 consecutive rows
      int bb = r0 >> 11;
      int t0 = r0 & 2047;
      #pragma unroll
      for (int ni = 0; ni < 4; ++ni) {
        int col = n0 + wc * 64 + ni * 16 + lr;
        int sel = col >> 10, rem = col & 1023;
        int h = rem >> 6, d = rem & 63;
        f32x4 v = acc[mi][ni];
        if (sel == 0) {
          size_t base = ((size_t)(bb * Hn + h) * Tn + t0) * Dn + d;
          #pragma unroll
          for (int r = 0; r < 4; ++r) Qb[base + (size_t)r * Dn] = f2bf(v[r] * 0.125f);
        } else if (sel == 1) {
          size_t base = ((size_t)(bb * Hn + h) * Tn + t0) * Dn + d;
          #pragma unroll
          for (int r = 0; r < 4; ++r) Kb[base + (size_t)r * Dn] = f2bf(v[r]);
        } else {
          size_t base = ((size_t)(bb * Hn + h) * Dn + d) * Tn + t0;
          ushort4 o;
          o.x = f2bf(v[0]); o.y = f2bf(v[1]); o.z = f2bf(v[2]); o.w = f2bf(v[3]);
          *(ushort4*)(Vb + base) = o;
        }
      }
    }
  } else {
    #pragma unroll
    for (int mi = 0; mi < 4; ++mi) {
      int r0 = m0 + wr * 64 + mi * 16 + lg * 4;
      #pragma unroll
      for (int ni = 0; ni < 4; ++ni) {
        int col = n0 + wc * 64 + ni * 16 + lr;
        float bv = bias[col];
        #pragma unroll
        for (int r = 0; r < 4; ++r)
          Out[(size_t)(r0 + r) * Cn + col] = acc[mi][ni][r] + bv;
      }
    }
  }
}

// ---------------- flash attention v7: 32x32 MFMA, 2-wave blocks, balanced ------
// grid: 1024 blocks x 128 thr. raw -> xcd = raw&7 (round-robin XCD), idx=raw>>3,
// cu = idx&31 (CU slot), j = idx>>5 (head-local). qt = (j&1) ? cu : 31-cu:
// the 4 blocks landing on one CU slot have tile counts summing to exactly 66
// -> uniform per-CU work by construction (no queue needed).
// Each block: one 64-row q-tile, 2 waves x 32 q-rows. K,V double-buffered in
// LDS (global_load_lds, XOR-swizzled). S^T = mfma32(K,Q): lane holds
// S[k = ks*32 + (g&3)+8*(g>>2)+4*hi][q = lane&31]. P repacked in-register via
// cvt_pk + shfl_xor(32). O^T = mfma32(V^T, P); transpose-out via LDS scratch.

__device__ __forceinline__ void stage_kv(const u16* __restrict__ K,
                                         const u16* __restrict__ Vt, int k0,
                                         u16* __restrict__ Kbuf, u16* __restrict__ Vbuf,
                                         int tid) {
  #pragma unroll
  for (int i = 0; i < 4; ++i) {
    int c = i * 128 + tid;            // chunk 0..511 (16 B each)
    int row = c >> 3;
    int js = (c & 7) ^ (row & 7);     // inverse-swizzled source chunk
    async16(K + (size_t)(k0 + row) * Dn + js * 8, Kbuf + c * 8);
    async16(Vt + (size_t)row * Tn + k0 + js * 8, Vbuf + c * 8);
  }
}

__launch_bounds__(128, 2)
__global__ void attn(const u16* __restrict__ Qb, const u16* __restrict__ Kb,
                     const u16* __restrict__ Vb, u16* __restrict__ Ob) {
  __shared__ u16 __attribute__((aligned(16))) Ks[2 * 4096];
  __shared__ u16 __attribute__((aligned(16))) Vs[2 * 4096];

  const int raw = blockIdx.x;
  const int xcd = raw & 7;
  const int idx = raw >> 3;                 // 0..127
  const int cu  = idx & 31;                 // CU slot within XCD
  const int j   = idx >> 5;                 // 0..3 head-local
  const int bh  = xcd * 4 + j;              // 4 heads per XCD -> L2 locality
  const int qt  = (j & 1) ? cu : 31 - cu;   // complementary work per CU slot
  const int q0  = qt * 64;
  const int nt  = qt + 1;

  const int tid = threadIdx.x;
  const int lane = tid & 63, wid = tid >> 6;          // wid 0..1
  const int l31 = lane & 31, hi = lane >> 5;
  const int bb = bh >> 4, h = bh & 15;

  const u16* Q  = Qb + (size_t)bh * Tn * Dn;
  const u16* K  = Kb + (size_t)bh * Tn * Dn;
  const u16* Vt = Vb + (size_t)bh * Dn * Tn;

  const int swz = lane & 7;                 // read-side XOR key (row&7 == lane&7)
  const int qg = q0 + wid * 32 + l31;       // this lane's q row

  // Q fragments (B operand): qf[c] = Q[qg][c*16 + hi*8 .. +7]
  bf16x8 qf[4];
  #pragma unroll
  for (int c = 0; c < 4; ++c)
    qf[c] = *(const bf16x8*)(Q + (size_t)qg * Dn + c * 16 + hi * 8);

  f32x16 o0 = {}, o1 = {};                  // O^T rows d = sub*32 + (g&3)+8*(g>>2)+4*hi
  float m = -1e30f, den = 0.f;

  int cur = 0;
  stage_kv(K, Vt, 0, Ks, Vs, tid);
  __syncthreads();

  for (int t = 0; t < nt; ++t) {
    const int k0 = t << 6;
    if (t + 1 < nt)
      stage_kv(K, Vt, (t + 1) << 6,
               Ks + (cur ^ 1) * 4096, Vs + (cur ^ 1) * 4096, tid);

    const u16* Kc = Ks + cur * 4096;
    const u16* Vc = Vs + cur * 4096;

    // S^T = K Q^T
    f32x16 s0 = {}, s1 = {};
    __builtin_amdgcn_s_setprio(1);
    #pragma unroll
    for (int c = 0; c < 4; ++c) {
      bf16x8 kf0 = *(const bf16x8*)(Kc + l31 * 64 + (((c * 2 + hi) ^ swz) * 8));
      bf16x8 kf1 = *(const bf16x8*)(Kc + (32 + l31) * 64 + (((c * 2 + hi) ^ swz) * 8));
      s0 = __builtin_amdgcn_mfma_f32_32x32x16_bf16(kf0, qf[c], s0, 0, 0, 0);
      s1 = __builtin_amdgcn_mfma_f32_32x32x16_bf16(kf1, qf[c], s1, 0, 0, 0);
    }
    __builtin_amdgcn_s_setprio(0);

    if (t == nt - 1) {                      // diagonal tile: mask k > q
      #pragma unroll
      for (int g = 0; g < 16; ++g) {
        int kl = (g & 3) + 8 * (g >> 2) + 4 * hi;
        if (k0 + kl > qg)      s0[g] = -1e30f;
        if (k0 + 32 + kl > qg) s1[g] = -1e30f;
      }
    }

    // row max: 31 in-lane + 1 cross-half shuffle
    float pm = s0[0];
    #pragma unroll
    for (int g = 1; g < 16; ++g) pm = fmaxf(pm, s0[g]);
    #pragma unroll
    for (int g = 0; g < 16; ++g) pm = fmaxf(pm, s1[g]);
    pm = fmaxf(pm, __shfl_xor(pm, 32));

    // defer-max (THR=8)
    if (!__all(pm - m <= 8.f)) {
      float mn = fmaxf(m, pm);
      float fac = __expf(m - mn);
      den *= fac;
      #pragma unroll
      for (int g = 0; g < 16; ++g) { o0[g] *= fac; o1[g] *= fac; }
      m = mn;
    }

    float sum = 0.f;
    #pragma unroll
    for (int g = 0; g < 16; ++g) { float p = __expf(s0[g] - m); s0[g] = p; sum += p; }
    #pragma unroll
    for (int g = 0; g < 16; ++g) { float p = __expf(s1[g] - m); s1[g] = p; sum += p; }
    sum += __shfl_xor(sum, 32);
    den += sum;

    // repack P in-register (verified in round 8): partner lane^32 holds the
    // missing half of each depth-16 chain.
    bf16x8 pfrag[4];
    #define MKFRAG(SV, C2, OUT) { \
      uint32_t u_ = pk_bf16(SV[8*(C2)+0], SV[8*(C2)+1]); \
      uint32_t v_ = pk_bf16(SV[8*(C2)+2], SV[8*(C2)+3]); \
      uint32_t w_ = pk_bf16(SV[8*(C2)+4], SV[8*(C2)+5]); \
      uint32_t z_ = pk_bf16(SV[8*(C2)+6], SV[8*(C2)+7]); \
      uint32_t us = __shfl_xor(u_, 32), vs = __shfl_xor(v_, 32); \
      uint32_t ws = __shfl_xor(w_, 32), zs = __shfl_xor(z_, 32); \
      u32x4 q4; \
      q4.x = hi ? ws : u_; q4.y = hi ? zs : v_; \
      q4.z = hi ? w_ : us; q4.w = hi ? z_ : vs; \
      OUT = __builtin_bit_cast(bf16x8, q4); }
    MKFRAG(s0, 0, pfrag[0]); MKFRAG(s0, 1, pfrag[1]);
    MKFRAG(s1, 0, pfrag[2]); MKFRAG(s1, 1, pfrag[3]);
    #undef MKFRAG

    // O^T += V^T P
    __builtin_amdgcn_s_setprio(1);
    #pragma unroll
    for (int kc = 0; kc < 4; ++kc) {
      bf16x8 vf0 = *(const bf16x8*)(Vc + l31 * 64 + (((kc * 2 + hi) ^ swz) * 8));
      bf16x8 vf1 = *(const bf16x8*)(Vc + (32 + l31) * 64 + (((kc * 2 + hi) ^ swz) * 8));
      o0 = __builtin_amdgcn_mfma_f32_32x32x16_bf16(vf0, pfrag[kc], o0, 0, 0, 0);
      o1 = __builtin_amdgcn_mfma_f32_32x32x16_bf16(vf1, pfrag[kc], o1, 0, 0, 0);
    }
    __builtin_amdgcn_s_setprio(0);

    __syncthreads();                 // drains vmcnt (stage t+1) + LDS reads done
    cur ^= 1;
  }

  // ---- epilogue: normalize, transpose O^T -> O rows via swizzled LDS ----
  float inv = 1.f / den;
  uint32_t* Owv = (uint32_t*)Ks + (wid << 10);   // per-wave 4KB: [32 q][32 u32 slots]
  #pragma unroll
  for (int e = 0; e < 16; e += 2) {
    uint32_t p0 = pk_bf16(o0[e] * inv, o0[e + 1] * inv);
    uint32_t p1 = pk_bf16(o1[e] * inv, o1[e + 1] * inv);
    int sl0 = ((e & 3) >> 1) + ((e >> 2) << 2) + (hi << 1);   // d/2 slot, dsub 0
    int sl1 = sl0 + 16;                                       // dsub 1
    Owv[(l31 << 5) + (((sl0 >> 2) ^ (l31 & 7)) << 2) + (sl0 & 3)] = p0;
    Owv[(l31 << 5) + (((sl1 >> 2) ^ (l31 & 7)) << 2) + (sl1 & 3)] = p1;
  }
  __syncthreads();
  u16* obase = Ob + ((size_t)(bb * Tn + q0 + wid * 32 + l31)) * Cn + h * Dn;
  #pragma unroll
  for (int i = 0; i < 4; ++i) {
    int c = (hi << 2) + i;                                    // 16B chunk = 8 d-values
    u32x4 vv = *(const u32x4*)&Owv[(l31 << 5) + ((c ^ (l31 & 7)) << 2)];
    *(u32x4*)(obase + c * 8) = vv;
  }
}

// ---------------- launch ----------------

extern "C" void kernel_launch(void* const* d_in, const int* in_sizes, int n_in,
                              void* d_out, int out_size, void* d_ws, size_t ws_size,
                              hipStream_t stream) {
  const float* x = (const float*)d_in[0];
  const float* w_qkv = (const float*)d_in[1];
  const float* w_proj = (const float*)d_in[2];
  const float* b_proj = (const float*)d_in[3];
  float* out = (float*)d_out;
  char* ws = (char*)d_ws;

  u16* xb     = (u16*)(ws);                       // 8 MB (reused as attn_out after gemm1)
  u16* wqkvT  = (u16*)(ws + (size_t)( 8u << 20)); // 6 MB
  u16* wprojT = (u16*)(ws + (size_t)(14u << 20)); // 2 MB
  u16* Qb     = (u16*)(ws + (size_t)(16u << 20)); // 8 MB
  u16* Kb     = (u16*)(ws + (size_t)(24u << 20)); // 8 MB
  u16* Vb     = (u16*)(ws + (size_t)(32u << 20)); // 8 MB  (total 40 MB)

  cvt_x<<<dim3(4096), dim3(256), 0, stream>>>(x, xb);
  cvt_T<1024, 3072><<<dim3(96, 32), dim3(256), 0, stream>>>(w_qkv, wqkvT);
  cvt_T<1024, 1024><<<dim3(32, 32), dim3(256), 0, stream>>>(w_proj, wprojT);

  gemm_bt<0><<<dim3(32 * 24), dim3(256), 0, stream>>>(xb, wqkvT, 3072,
                                                      Qb, Kb, Vb, nullptr, nullptr);
  attn<<<dim3(1024), dim3(128), 0, stream>>>(Qb, Kb, Vb, xb /* attn_out */);
  gemm_bt<1><<<dim3(32 * 8), dim3(256), 0, stream>>>(xb, wprojT, 1024,
                                                     nullptr, nullptr, nullptr, out, b_proj);
}

// Round 10
// 124.256 us; speedup vs baseline: 1.0272x; 1.0272x over previous
//
#include <hip/hip_runtime.h>
#include <stdint.h>

#define Bn 2
#define Tn 2048
#define Cn 1024
#define Hn 16
#define Dn 64
#define Mn (Bn*Tn)

typedef __attribute__((ext_vector_type(8))) short bf16x8;
typedef __attribute__((ext_vector_type(4))) float f32x4;
typedef __attribute__((ext_vector_type(4))) unsigned int u32x4;
typedef __attribute__((ext_vector_type(2))) unsigned int u32x2;
typedef unsigned short u16;

__device__ __forceinline__ u16 f2bf(float f) {
  union { float f; uint32_t u; } v; v.f = f;
  uint32_t u = v.u;
  return (u16)((u + 0x7fffu + ((u >> 16) & 1u)) >> 16);
}

__device__ __forceinline__ uint32_t pk_bf16(float lo, float hi) {
  uint32_t r;
  asm volatile("v_cvt_pk_bf16_f32 %0, %1, %2" : "=v"(r) : "v"(lo), "v"(hi));
  return r;
}

__device__ __forceinline__ void async16(const void* g, void* lds) {
  __builtin_amdgcn_global_load_lds((const __attribute__((address_space(1))) void*)g,
                                   (__attribute__((address_space(3))) void*)lds,
                                   16, 0, 0);
}

// ---------------- conversion kernels ----------------

__global__ void cvt_x(const float* __restrict__ x, u16* __restrict__ xb) {
  int i = (blockIdx.x * 256 + threadIdx.x) * 4;
  float4 v = *(const float4*)(x + i);
  ushort4 o;
  o.x = f2bf(v.x); o.y = f2bf(v.y); o.z = f2bf(v.z); o.w = f2bf(v.w);
  *(ushort4*)(xb + i) = o;
}

// in: [K][N] f32 row-major  ->  out: [N][K] bf16 row-major (transpose + convert)
template<int K, int N>
__global__ void cvt_T(const float* __restrict__ in, u16* __restrict__ out) {
  __shared__ float tile[32][33];
  int n0 = blockIdx.x * 32, k0 = blockIdx.y * 32;
  int tx = threadIdx.x & 31, ty = threadIdx.x >> 5;  // 32 x 8
  #pragma unroll
  for (int i = 0; i < 32; i += 8)
    tile[ty + i][tx] = in[(size_t)(k0 + ty + i) * N + n0 + tx];
  __syncthreads();
  #pragma unroll
  for (int i = 0; i < 32; i += 8)
    out[(size_t)(n0 + ty + i) * K + k0 + tx] = f2bf(tile[tx][ty + i]);
}

// ---------------- GEMM:  C[M,N] = A[M,K=1024] * Bt[N,K]^T  (bf16 in, f32 acc) ----------------

template<int EPI>
__launch_bounds__(256, 3)
__global__ void gemm_bt(const u16* __restrict__ A, const u16* __restrict__ Bt, int N,
                        u16* __restrict__ Qb, u16* __restrict__ Kb, u16* __restrict__ Vb,
                        float* __restrict__ Out, const float* __restrict__ bias) {
  constexpr int Kd = 1024;
  __shared__ u16 As[128][64];
  __shared__ u16 Bs[128][64];
  const int nT = N >> 7;
  const int cpx = gridDim.x >> 3;
  const int wg = (blockIdx.x & 7) * cpx + (blockIdx.x >> 3);   // XCD-chunked
  const int m0 = (wg / nT) << 7;
  const int n0 = (wg % nT) << 7;
  const int tid = threadIdx.x;
  const int lane = tid & 63, wid = tid >> 6;
  const int wr = wid >> 1, wc = wid & 1;
  const int lr = lane & 15, lg = lane >> 4;

  f32x4 acc[4][4] = {};

  for (int kb = 0; kb < Kd; kb += 64) {
    #pragma unroll
    for (int i = 0; i < 4; ++i) {
      int c = (wid * 4 + i) * 64 + lane;     // chunk id 0..1023
      int row = c >> 3, ko = (c & 7) << 3;
      async16(A + (size_t)(m0 + row) * Kd + kb + ko, &As[0][0] + c * 8);
      async16(Bt + (size_t)(n0 + row) * Kd + kb + ko, &Bs[0][0] + c * 8);
    }
    __syncthreads();
    bf16x8 af[2][4], bf[2][4];
    #pragma unroll
    for (int kc = 0; kc < 2; ++kc) {
      #pragma unroll
      for (int mi = 0; mi < 4; ++mi) {
        af[kc][mi] = *(const bf16x8*)&As[wr * 64 + mi * 16 + lr][kc * 32 + lg * 8];
        bf[kc][mi] = *(const bf16x8*)&Bs[wc * 64 + mi * 16 + lr][kc * 32 + lg * 8];
      }
    }
    #pragma unroll
    for (int kc = 0; kc < 2; ++kc)
      #pragma unroll
      for (int mi = 0; mi < 4; ++mi)
        #pragma unroll
        for (int ni = 0; ni < 4; ++ni)
          acc[mi][ni] = __builtin_amdgcn_mfma_f32_16x16x32_bf16(af[kc][mi], bf[kc][ni], acc[mi][ni], 0, 0, 0);
    __syncthreads();
  }

  if constexpr (EPI == 0) {
    #pragma unroll
    for (int mi = 0; mi < 4; ++mi) {
      int r0 = m0 + wr * 64 + mi * 16 + lg * 4;   // 4 consecutive rows
      int bb = r0 >> 11;
      int t0 = r0 & 2047;
      #pragma unroll
      for (int ni = 0; ni < 4; ++ni) {
        int col = n0 + wc * 64 + ni * 16 + lr;
        int sel = col >> 10, rem = col & 1023;
        int h = rem >> 6, d = rem & 63;
        f32x4 v = acc[mi][ni];
        if (sel == 0) {
          size_t base = ((size_t)(bb * Hn + h) * Tn + t0) * Dn + d;
          #pragma unroll
          for (int r = 0; r < 4; ++r) Qb[base + (size_t)r * Dn] = f2bf(v[r] * 0.125f);
        } else if (sel == 1) {
          size_t base = ((size_t)(bb * Hn + h) * Tn + t0) * Dn + d;
          #pragma unroll
          for (int r = 0; r < 4; ++r) Kb[base + (size_t)r * Dn] = f2bf(v[r]);
        } else {
          size_t base = ((size_t)(bb * Hn + h) * Dn + d) * Tn + t0;
          ushort4 o;
          o.x = f2bf(v[0]); o.y = f2bf(v[1]); o.z = f2bf(v[2]); o.w = f2bf(v[3]);
          *(ushort4*)(Vb + base) = o;
        }
      }
    }
  } else {
    #pragma unroll
    for (int mi = 0; mi < 4; ++mi) {
      int r0 = m0 + wr * 64 + mi * 16 + lg * 4;
      #pragma unroll
      for (int ni = 0; ni < 4; ++ni) {
        int col = n0 + wc * 64 + ni * 16 + lr;
        float bv = bias[col];
        #pragma unroll
        for (int r = 0; r < 4; ++r)
          Out[(size_t)(r0 + r) * Cn + col] = acc[mi][ni][r] + bv;
      }
    }
  }
}

// ---------------- flash attention v8: r7 structure + in-register P -------------
// grid: 1024 blocks = 8 XCD x (4 bh-local x 32 q-tiles, longest first).
// 256 thr = 4 waves, each wave owns 16 q rows. K,V double-buffered in LDS
// (global_load_lds, XOR-swizzled). LDS = 32KB exactly -> 4 blocks/CU
// (16 waves/CU). S^T = mfma(K,Q): lane holds S[k=f*16+lg*4+r][q=lr].
// P built IN-REGISTER for PV's B-operand: 8 cvt_pk + 16 shfl + 8 selects
// (replaces the 9KB P_lds buffer). Verified mapping: word w of fragment kc
// = pk{A,B}[2kc+(lg>>1)] taken from srclane (lg&1)*32 + (w>=2?16:0) + lr.
// O^T = mfma(V^T, P); output transpose via Ks reused as scratch.

__device__ __forceinline__ void stage_kv(const u16* __restrict__ K,
                                         const u16* __restrict__ Vt, int k0,
                                         u16* __restrict__ Kbuf, u16* __restrict__ Vbuf,
                                         int tid) {
  #pragma unroll
  for (int i = 0; i < 2; ++i) {
    int c = i * 256 + tid;            // chunk 0..511 (16 B each)
    int row = c >> 3;
    int js = (c & 7) ^ (row & 7);     // inverse-swizzled source chunk
    async16(K + (size_t)(k0 + row) * Dn + js * 8, Kbuf + c * 8);
    async16(Vt + (size_t)row * Tn + k0 + js * 8, Vbuf + c * 8);
  }
}

__launch_bounds__(256, 4)
__global__ void attn(const u16* __restrict__ Qb, const u16* __restrict__ Kb,
                     const u16* __restrict__ Vb, u16* __restrict__ Ob) {
  __shared__ u16 __attribute__((aligned(16))) Ks[2 * 4096];
  __shared__ u16 __attribute__((aligned(16))) Vs[2 * 4096];

  const int raw = blockIdx.x;
  const int xcd = raw & 7;
  const int idx = raw >> 3;                 // 0..127
  const int bh  = xcd * 4 + (idx & 3);      // 4 heads per XCD -> L2 locality
  const int qt  = 31 - (idx >> 2);          // longest q-tiles dispatched first
  const int q0  = qt * 64;
  const int nt  = qt + 1;

  const int tid = threadIdx.x;
  const int lane = tid & 63, wid = tid >> 6;
  const int lr = lane & 15, lg = lane >> 4;
  const int bb = bh >> 4, h = bh & 15;

  const u16* Q  = Qb + (size_t)bh * Tn * Dn;
  const u16* K  = Kb + (size_t)bh * Tn * Dn;
  const u16* Vt = Vb + (size_t)bh * Dn * Tn;

  const int swz = (lr & 7);           // read-side XOR key for K/V tiles
  const int qoff = wid * 16 + lr;     // q offset within 64-row q-tile
  const int koff0 = lg * 4;           // k offset base for this lane
  const int s0l = ((lane & 16) << 1) | (lane & 15);   // (lg&1)*32 + lr
  const bool hiF = lane >= 32;                        // lg>>1

  // Q fragments (B operand): rows q0 + qoff
  bf16x8 qf[2];
  qf[0] = *(const bf16x8*)(Q + (size_t)(q0 + qoff) * Dn + lg * 8);
  qf[1] = *(const bf16x8*)(Q + (size_t)(q0 + qoff) * Dn + 32 + lg * 8);

  f32x4 o[4] = {};                    // O^T: o[f][r] = O[dv=f*16+lg*4+r][q=lr]
  float m = -1e30f, l = 0.f;

  int cur = 0;
  stage_kv(K, Vt, 0, Ks, Vs, tid);
  __syncthreads();

  for (int t = 0; t < nt; ++t) {
    if (t + 1 < nt)
      stage_kv(K, Vt, (t + 1) << 6,
               Ks + (cur ^ 1) * 4096, Vs + (cur ^ 1) * 4096, tid);

    const u16* Kc = Ks + cur * 4096;
    const u16* Vc = Vs + cur * 4096;

    // S^T = K Q^T : s[f][r] = S[k = f*16+lg*4+r][q = lr]
    f32x4 s[4] = {};
    __builtin_amdgcn_s_setprio(1);
    #pragma unroll
    for (int f = 0; f < 4; ++f) {
      const int row = f * 16 + lr;
      #pragma unroll
      for (int kc = 0; kc < 2; ++kc) {
        bf16x8 kf = *(const bf16x8*)(Kc + row * 64 + (((kc * 4 + lg) ^ swz) * 8));
        s[f] = __builtin_amdgcn_mfma_f32_16x16x32_bf16(kf, qf[kc], s[f], 0, 0, 0);
      }
    }
    __builtin_amdgcn_s_setprio(0);

    if (t == nt - 1) {               // diagonal tile: mask k > q
      #pragma unroll
      for (int f = 0; f < 4; ++f)
        #pragma unroll
        for (int r = 0; r < 4; ++r)
          if (f * 16 + koff0 + r > qoff) s[f][r] = -1e30f;
    }

    // per-lane row max over 16 k values, then across the 4 lg groups
    float pm = fmaxf(fmaxf(fmaxf(s[0][0], s[0][1]), fmaxf(s[0][2], s[0][3])),
                     fmaxf(fmaxf(s[1][0], s[1][1]), fmaxf(s[1][2], s[1][3])));
    float pm2 = fmaxf(fmaxf(fmaxf(s[2][0], s[2][1]), fmaxf(s[2][2], s[2][3])),
                      fmaxf(fmaxf(s[3][0], s[3][1]), fmaxf(s[3][2], s[3][3])));
    pm = fmaxf(pm, pm2);
    pm = fmaxf(pm, __shfl_xor(pm, 16));
    pm = fmaxf(pm, __shfl_xor(pm, 32));

    // defer-max: only rescale when the max grew by more than THR=8
    if (!__all(pm - m <= 8.f)) {
      float mn = fmaxf(m, pm);
      float fac = __expf(m - mn);
      l *= fac;
      #pragma unroll
      for (int f = 0; f < 4; ++f) {
        o[f][0] *= fac; o[f][1] *= fac; o[f][2] *= fac; o[f][3] *= fac;
      }
      m = mn;
    }

    float sum = 0.f;
    #pragma unroll
    for (int f = 0; f < 4; ++f) {
      #pragma unroll
      for (int r = 0; r < 4; ++r) {
        float p = __expf(s[f][r] - m);
        s[f][r] = p;
        sum += p;
      }
    }
    sum += __shfl_xor(sum, 16);
    sum += __shfl_xor(sum, 32);
    l += sum;

    // pack P rows (k pairs) to bf16 words
    uint32_t pkA[4], pkB[4];
    #pragma unroll
    for (int f = 0; f < 4; ++f) {
      pkA[f] = pk_bf16(s[f][0], s[f][1]);
      pkB[f] = pk_bf16(s[f][2], s[f][3]);
    }

    // O^T += V^T P with in-register P fragments
    __builtin_amdgcn_s_setprio(1);
    #pragma unroll
    for (int kc = 0; kc < 2; ++kc) {
      uint32_t a0 = __shfl(pkA[2 * kc], s0l),      a1 = __shfl(pkA[2 * kc + 1], s0l);
      uint32_t b0 = __shfl(pkB[2 * kc], s0l),      b1 = __shfl(pkB[2 * kc + 1], s0l);
      uint32_t c0 = __shfl(pkA[2 * kc], s0l + 16), c1 = __shfl(pkA[2 * kc + 1], s0l + 16);
      uint32_t d0 = __shfl(pkB[2 * kc], s0l + 16), d1 = __shfl(pkB[2 * kc + 1], s0l + 16);
      u32x4 q4;
      q4.x = hiF ? a1 : a0;  q4.y = hiF ? b1 : b0;
      q4.z = hiF ? c1 : c0;  q4.w = hiF ? d1 : d0;
      bf16x8 pf = __builtin_bit_cast(bf16x8, q4);
      #pragma unroll
      for (int f = 0; f < 4; ++f) {
        const int row = f * 16 + lr;
        bf16x8 vf = *(const bf16x8*)(Vc + row * 64 + (((kc * 4 + lg) ^ swz) * 8));
        o[f] = __builtin_amdgcn_mfma_f32_16x16x32_bf16(vf, pf, o[f], 0, 0, 0);
      }
    }
    __builtin_amdgcn_s_setprio(0);

    __syncthreads();                 // drains vmcnt (stage t+1) + LDS reads done
    cur ^= 1;
  }

  // normalize, transpose O^T -> O via Ks reused as scratch, store [B*T][C]
  float inv = 1.f / l;
  uint32_t* scr = (uint32_t*)Ks + wid * 576;      // per-wave [16 q][36 u32]
  #pragma unroll
  for (int f = 0; f < 4; ++f) {
    u32x2 w;
    w.x = pk_bf16(o[f][0] * inv, o[f][1] * inv);
    w.y = pk_bf16(o[f][2] * inv, o[f][3] * inv);
    *(u32x2*)&scr[lr * 36 + f * 8 + lg * 2] = w;  // scr[q=lr][d = f*16+lg*4 ..+3]
  }
  // each of the 4 lg-lanes sharing q-row lr stores 16 d-values (2 x 16B)
  u32x4 r0 = *(const u32x4*)&scr[lr * 36 + lg * 8];       // d = lg*16 .. +7
  u32x4 r1 = *(const u32x4*)&scr[lr * 36 + lg * 8 + 4];   // d = lg*16+8 .. +15
  u16* obase = Ob + ((size_t)(bb * Tn + q0 + qoff)) * Cn + h * Dn + lg * 16;
  *(u32x4*)(obase) = r0;
  *(u32x4*)(obase + 8) = r1;
}

// ---------------- launch ----------------

extern "C" void kernel_launch(void* const* d_in, const int* in_sizes, int n_in,
                              void* d_out, int out_size, void* d_ws, size_t ws_size,
                              hipStream_t stream) {
  const float* x = (const float*)d_in[0];
  const float* w_qkv = (const float*)d_in[1];
  const float* w_proj = (const float*)d_in[2];
  const float* b_proj = (const float*)d_in[3];
  float* out = (float*)d_out;
  char* ws = (char*)d_ws;

  u16* xb     = (u16*)(ws);                       // 8 MB (reused as attn_out after gemm1)
  u16* wqkvT  = (u16*)(ws + (size_t)( 8u << 20)); // 6 MB
  u16* wprojT = (u16*)(ws + (size_t)(14u << 20)); // 2 MB
  u16* Qb     = (u16*)(ws + (size_t)(16u << 20)); // 8 MB
  u16* Kb     = (u16*)(ws + (size_t)(24u << 20)); // 8 MB
  u16* Vb     = (u16*)(ws + (size_t)(32u << 20)); // 8 MB  (total 40 MB)

  cvt_x<<<dim3(4096), dim3(256), 0, stream>>>(x, xb);
  cvt_T<1024, 3072><<<dim3(96, 32), dim3(256), 0, stream>>>(w_qkv, wqkvT);
  cvt_T<1024, 1024><<<dim3(32, 32), dim3(256), 0, stream>>>(w_proj, wprojT);

  gemm_bt<0><<<dim3(32 * 24), dim3(256), 0, stream>>>(xb, wqkvT, 3072,
                                                      Qb, Kb, Vb, nullptr, nullptr);
  attn<<<dim3(1024), dim3(256), 0, stream>>>(Qb, Kb, Vb, xb /* attn_out */);
  gemm_bt<1><<<dim3(32 * 8), dim3(256), 0, stream>>>(xb, wprojT, 1024,
                                                     nullptr, nullptr, nullptr, out, b_proj);
}

// Round 11
// 122.030 us; speedup vs baseline: 1.0459x; 1.0182x over previous
//
#include <hip/hip_runtime.h>
#include <stdint.h>

#define Bn 2
#define Tn 2048
#define Cn 1024
#define Hn 16
#define Dn 64
#define Mn (Bn*Tn)

typedef __attribute__((ext_vector_type(8))) short bf16x8;
typedef __attribute__((ext_vector_type(4))) float f32x4;
typedef __attribute__((ext_vector_type(4))) unsigned int u32x4;
typedef __attribute__((ext_vector_type(2))) unsigned int u32x2;
typedef unsigned short u16;

__device__ __forceinline__ u16 f2bf(float f) {
  union { float f; uint32_t u; } v; v.f = f;
  uint32_t u = v.u;
  return (u16)((u + 0x7fffu + ((u >> 16) & 1u)) >> 16);
}

__device__ __forceinline__ uint32_t pk_bf16(float lo, float hi) {
  uint32_t r;
  asm volatile("v_cvt_pk_bf16_f32 %0, %1, %2" : "=v"(r) : "v"(lo), "v"(hi));
  return r;
}

__device__ __forceinline__ void async16(const void* g, void* lds) {
  __builtin_amdgcn_global_load_lds((const __attribute__((address_space(1))) void*)g,
                                   (__attribute__((address_space(3))) void*)lds,
                                   16, 0, 0);
}

// ---------------- conversion kernels ----------------

__global__ void cvt_x(const float* __restrict__ x, u16* __restrict__ xb) {
  int i = (blockIdx.x * 256 + threadIdx.x) * 4;
  float4 v = *(const float4*)(x + i);
  ushort4 o;
  o.x = f2bf(v.x); o.y = f2bf(v.y); o.z = f2bf(v.z); o.w = f2bf(v.w);
  *(ushort4*)(xb + i) = o;
}

// in: [K][N] f32 row-major  ->  out: [N][K] bf16 row-major (transpose + convert)
template<int K, int N>
__global__ void cvt_T(const float* __restrict__ in, u16* __restrict__ out) {
  __shared__ float tile[32][33];
  int n0 = blockIdx.x * 32, k0 = blockIdx.y * 32;
  int tx = threadIdx.x & 31, ty = threadIdx.x >> 5;  // 32 x 8
  #pragma unroll
  for (int i = 0; i < 32; i += 8)
    tile[ty + i][tx] = in[(size_t)(k0 + ty + i) * N + n0 + tx];
  __syncthreads();
  #pragma unroll
  for (int i = 0; i < 32; i += 8)
    out[(size_t)(n0 + ty + i) * K + k0 + tx] = f2bf(tile[tx][ty + i]);
}

// ---------------- GEMM:  C[M,N] = A[M,K=1024] * Bt[N,K]^T  (bf16 in, f32 acc) ----------------

template<int EPI>
__launch_bounds__(256, 3)
__global__ void gemm_bt(const u16* __restrict__ A, const u16* __restrict__ Bt, int N,
                        u16* __restrict__ Qb, u16* __restrict__ Kb, u16* __restrict__ Vb,
                        float* __restrict__ Out, const float* __restrict__ bias) {
  constexpr int Kd = 1024;
  __shared__ u16 As[128][64];
  __shared__ u16 Bs[128][64];
  const int nT = N >> 7;
  const int cpx = gridDim.x >> 3;
  const int wg = (blockIdx.x & 7) * cpx + (blockIdx.x >> 3);   // XCD-chunked
  const int m0 = (wg / nT) << 7;
  const int n0 = (wg % nT) << 7;
  const int tid = threadIdx.x;
  const int lane = tid & 63, wid = tid >> 6;
  const int wr = wid >> 1, wc = wid & 1;
  const int lr = lane & 15, lg = lane >> 4;

  f32x4 acc[4][4] = {};

  for (int kb = 0; kb < Kd; kb += 64) {
    #pragma unroll
    for (int i = 0; i < 4; ++i) {
      int c = (wid * 4 + i) * 64 + lane;     // chunk id 0..1023
      int row = c >> 3, ko = (c & 7) << 3;
      async16(A + (size_t)(m0 + row) * Kd + kb + ko, &As[0][0] + c * 8);
      async16(Bt + (size_t)(n0 + row) * Kd + kb + ko, &Bs[0][0] + c * 8);
    }
    __syncthreads();
    bf16x8 af[2][4], bf[2][4];
    #pragma unroll
    for (int kc = 0; kc < 2; ++kc) {
      #pragma unroll
      for (int mi = 0; mi < 4; ++mi) {
        af[kc][mi] = *(const bf16x8*)&As[wr * 64 + mi * 16 + lr][kc * 32 + lg * 8];
        bf[kc][mi] = *(const bf16x8*)&Bs[wc * 64 + mi * 16 + lr][kc * 32 + lg * 8];
      }
    }
    #pragma unroll
    for (int kc = 0; kc < 2; ++kc)
      #pragma unroll
      for (int mi = 0; mi < 4; ++mi)
        #pragma unroll
        for (int ni = 0; ni < 4; ++ni)
          acc[mi][ni] = __builtin_amdgcn_mfma_f32_16x16x32_bf16(af[kc][mi], bf[kc][ni], acc[mi][ni], 0, 0, 0);
    __syncthreads();
  }

  if constexpr (EPI == 0) {
    #pragma unroll
    for (int mi = 0; mi < 4; ++mi) {
      int r0 = m0 + wr * 64 + mi * 16 + lg * 4;   // 4 consecutive rows
      int bb = r0 >> 11;
      int t0 = r0 & 2047;
      #pragma unroll
      for (int ni = 0; ni < 4; ++ni) {
        int col = n0 + wc * 64 + ni * 16 + lr;
        int sel = col >> 10, rem = col & 1023;
        int h = rem >> 6, d = rem & 63;
        f32x4 v = acc[mi][ni];
        if (sel == 0) {
          // Q pre-scaled by (1/sqrt(D)) * log2(e) so attn works in exp2 domain
          size_t base = ((size_t)(bb * Hn + h) * Tn + t0) * Dn + d;
          #pragma unroll
          for (int r = 0; r < 4; ++r) Qb[base + (size_t)r * Dn] = f2bf(v[r] * 0.18033688f);
        } else if (sel == 1) {
          size_t base = ((size_t)(bb * Hn + h) * Tn + t0) * Dn + d;
          #pragma unroll
          for (int r = 0; r < 4; ++r) Kb[base + (size_t)r * Dn] = f2bf(v[r]);
        } else {
          size_t base = ((size_t)(bb * Hn + h) * Dn + d) * Tn + t0;
          ushort4 o;
          o.x = f2bf(v[0]); o.y = f2bf(v[1]); o.z = f2bf(v[2]); o.w = f2bf(v[3]);
          *(ushort4*)(Vb + base) = o;
        }
      }
    }
  } else {
    #pragma unroll
    for (int mi = 0; mi < 4; ++mi) {
      int r0 = m0 + wr * 64 + mi * 16 + lg * 4;
      #pragma unroll
      for (int ni = 0; ni < 4; ++ni) {
        int col = n0 + wc * 64 + ni * 16 + lr;
        float bv = bias[col];
        #pragma unroll
        for (int r = 0; r < 4; ++r)
          Out[(size_t)(r0 + r) * Cn + col] = acc[mi][ni][r] + bv;
      }
    }
  }
}

// ---------------- flash attention v9: r7 structure, 40KB LDS, exp2 softmax -----
// grid: 1024 blocks = 8 XCD x (4 bh-local x 32 q-tiles, longest first).
// 256 thr = 4 waves, each wave owns 16 q rows. K,V double-buffered in LDS
// (global_load_lds, XOR-swizzled). P via per-wave LDS [16][32]u32 with XOR
// swizzle (u32idx ^= 4*(lr&7)) instead of padding -> total LDS 40960 B =
// exactly 4 blocks/CU (16 waves/CU). Softmax in exp2 domain (Q carries log2e).
// S^T = mfma(K,Q): lane holds S[k=f*16+lg*4+r][q=lr].
// PV = mfma(V^T, P): O^T[dv=f*16+lg*4+r][q=lr].

__device__ __forceinline__ void stage_kv(const u16* __restrict__ K,
                                         const u16* __restrict__ Vt, int k0,
                                         u16* __restrict__ Kbuf, u16* __restrict__ Vbuf,
                                         int tid) {
  #pragma unroll
  for (int i = 0; i < 2; ++i) {
    int c = i * 256 + tid;            // chunk 0..511 (16 B each)
    int row = c >> 3;
    int js = (c & 7) ^ (row & 7);     // inverse-swizzled source chunk
    async16(K + (size_t)(k0 + row) * Dn + js * 8, Kbuf + c * 8);
    async16(Vt + (size_t)row * Tn + k0 + js * 8, Vbuf + c * 8);
  }
}

__launch_bounds__(256, 4)
__global__ void attn(const u16* __restrict__ Qb, const u16* __restrict__ Kb,
                     const u16* __restrict__ Vb, u16* __restrict__ Ob) {
  __shared__ u16 __attribute__((aligned(16))) Ks[2 * 4096];
  __shared__ u16 __attribute__((aligned(16))) Vs[2 * 4096];
  __shared__ uint32_t __attribute__((aligned(16))) P32[4][16][32]; // per-wave, XOR-swizzled

  const int raw = blockIdx.x;
  const int xcd = raw & 7;
  const int idx = raw >> 3;                 // 0..127
  const int bh  = xcd * 4 + (idx & 3);      // 4 heads per XCD -> L2 locality
  const int qt  = 31 - (idx >> 2);          // longest q-tiles dispatched first
  const int q0  = qt * 64;
  const int nt  = qt + 1;

  const int tid = threadIdx.x;
  const int lane = tid & 63, wid = tid >> 6;
  const int lr = lane & 15, lg = lane >> 4;
  const int bb = bh >> 4, h = bh & 15;

  const u16* Q  = Qb + (size_t)bh * Tn * Dn;
  const u16* K  = Kb + (size_t)bh * Tn * Dn;
  const u16* Vt = Vb + (size_t)bh * Dn * Tn;

  const int swz = (lr & 7);           // read-side XOR key for K/V tiles
  const int pswz = (lr & 7) << 2;     // P32 u32-index XOR key (bank spread)
  const int qoff = wid * 16 + lr;     // q offset within 64-row q-tile
  const int koff0 = lg * 4;           // k offset base for this lane

  // Q fragments (B operand): rows q0 + qoff
  bf16x8 qf[2];
  qf[0] = *(const bf16x8*)(Q + (size_t)(q0 + qoff) * Dn + lg * 8);
  qf[1] = *(const bf16x8*)(Q + (size_t)(q0 + qoff) * Dn + 32 + lg * 8);

  f32x4 o[4] = {};                    // O^T: o[f][r] = O[dv=f*16+lg*4+r][q=lr]
  float m = -1e30f, l = 0.f;

  int cur = 0;
  stage_kv(K, Vt, 0, Ks, Vs, tid);
  __syncthreads();

  for (int t = 0; t < nt; ++t) {
    if (t + 1 < nt)
      stage_kv(K, Vt, (t + 1) << 6,
               Ks + (cur ^ 1) * 4096, Vs + (cur ^ 1) * 4096, tid);

    const u16* Kc = Ks + cur * 4096;
    const u16* Vc = Vs + cur * 4096;

    // S^T = K Q^T : s[f][r] = S[k = f*16+lg*4+r][q = lr]  (log2 units)
    f32x4 s[4] = {};
    __builtin_amdgcn_s_setprio(1);
    #pragma unroll
    for (int f = 0; f < 4; ++f) {
      const int row = f * 16 + lr;
      #pragma unroll
      for (int kc = 0; kc < 2; ++kc) {
        bf16x8 kf = *(const bf16x8*)(Kc + row * 64 + (((kc * 4 + lg) ^ swz) * 8));
        s[f] = __builtin_amdgcn_mfma_f32_16x16x32_bf16(kf, qf[kc], s[f], 0, 0, 0);
      }
    }
    __builtin_amdgcn_s_setprio(0);

    if (t == nt - 1) {               // diagonal tile: mask k > q
      #pragma unroll
      for (int f = 0; f < 4; ++f)
        #pragma unroll
        for (int r = 0; r < 4; ++r)
          if (f * 16 + koff0 + r > qoff) s[f][r] = -1e30f;
    }

    // per-lane row max over 16 k values, then across the 4 lg groups
    float pm = fmaxf(fmaxf(fmaxf(s[0][0], s[0][1]), fmaxf(s[0][2], s[0][3])),
                     fmaxf(fmaxf(s[1][0], s[1][1]), fmaxf(s[1][2], s[1][3])));
    float pm2 = fmaxf(fmaxf(fmaxf(s[2][0], s[2][1]), fmaxf(s[2][2], s[2][3])),
                      fmaxf(fmaxf(s[3][0], s[3][1]), fmaxf(s[3][2], s[3][3])));
    pm = fmaxf(pm, pm2);
    pm = fmaxf(pm, __shfl_xor(pm, 16));
    pm = fmaxf(pm, __shfl_xor(pm, 32));

    // defer-max: rescale only when max grew by more than 11.5 (= 8/ln2-ish)
    if (!__all(pm - m <= 11.5f)) {
      float mn = fmaxf(m, pm);
      float fac = exp2f(m - mn);
      l *= fac;
      #pragma unroll
      for (int f = 0; f < 4; ++f) {
        o[f][0] *= fac; o[f][1] *= fac; o[f][2] *= fac; o[f][3] *= fac;
      }
      m = mn;
    }

    float sum = 0.f;
    #pragma unroll
    for (int f = 0; f < 4; ++f) {
      #pragma unroll
      for (int r = 0; r < 4; ++r) {
        float p = exp2f(s[f][r] - m);
        s[f][r] = p;
        sum += p;
      }
    }
    sum += __shfl_xor(sum, 16);
    sum += __shfl_xor(sum, 32);
    l += sum;

    // P -> per-wave LDS [q][k], swizzled u32 pairs (4 consecutive k per lane)
    #pragma unroll
    for (int f = 0; f < 4; ++f) {
      u32x2 w;
      w.x = pk_bf16(s[f][0], s[f][1]);
      w.y = pk_bf16(s[f][2], s[f][3]);
      *(u32x2*)&P32[wid][lr][(f * 8 + lg * 2) ^ pswz] = w;
    }

    // O^T += V^T P : A = V^T fragment (dv rows), B = P fragment ([k][q])
    __builtin_amdgcn_s_setprio(1);
    #pragma unroll
    for (int kc = 0; kc < 2; ++kc) {
      u32x4 p4 = *(const u32x4*)&P32[wid][lr][(kc * 16 + lg * 4) ^ pswz];
      bf16x8 pf = __builtin_bit_cast(bf16x8, p4);
      #pragma unroll
      for (int f = 0; f < 4; ++f) {
        const int row = f * 16 + lr;
        bf16x8 vf = *(const bf16x8*)(Vc + row * 64 + (((kc * 4 + lg) ^ swz) * 8));
        o[f] = __builtin_amdgcn_mfma_f32_16x16x32_bf16(vf, pf, o[f], 0, 0, 0);
      }
    }
    __builtin_amdgcn_s_setprio(0);

    __syncthreads();                 // drains vmcnt (stage t+1) + LDS reads done
    cur ^= 1;
  }

  // normalize, transpose O^T -> O via P32 (same swizzle), store [B*T][C]
  float inv = 1.f / l;
  #pragma unroll
  for (int f = 0; f < 4; ++f) {
    u32x2 w;
    w.x = pk_bf16(o[f][0] * inv, o[f][1] * inv);
    w.y = pk_bf16(o[f][2] * inv, o[f][3] * inv);
    *(u32x2*)&P32[wid][lr][(f * 8 + lg * 2) ^ pswz] = w;  // [q=lr][d=f*16+lg*4..+3]
  }
  // each of the 4 lg-lanes sharing q-row lr stores 16 d-values (2 x 16B)
  u32x4 r0 = *(const u32x4*)&P32[wid][lr][(lg * 8) ^ pswz];       // d = lg*16..+7
  u32x4 r1 = *(const u32x4*)&P32[wid][lr][(lg * 8 + 4) ^ pswz];   // d = lg*16+8..+15
  u16* obase = Ob + ((size_t)(bb * Tn + q0 + qoff)) * Cn + h * Dn + lg * 16;
  *(u32x4*)(obase) = r0;
  *(u32x4*)(obase + 8) = r1;
}

// ---------------- launch ----------------

extern "C" void kernel_launch(void* const* d_in, const int* in_sizes, int n_in,
                              void* d_out, int out_size, void* d_ws, size_t ws_size,
                              hipStream_t stream) {
  const float* x = (const float*)d_in[0];
  const float* w_qkv = (const float*)d_in[1];
  const float* w_proj = (const float*)d_in[2];
  const float* b_proj = (const float*)d_in[3];
  float* out = (float*)d_out;
  char* ws = (char*)d_ws;

  u16* xb     = (u16*)(ws);                       // 8 MB (reused as attn_out after gemm1)
  u16* wqkvT  = (u16*)(ws + (size_t)( 8u << 20)); // 6 MB
  u16* wprojT = (u16*)(ws + (size_t)(14u << 20)); // 2 MB
  u16* Qb     = (u16*)(ws + (size_t)(16u << 20)); // 8 MB
  u16* Kb     = (u16*)(ws + (size_t)(24u << 20)); // 8 MB
  u16* Vb     = (u16*)(ws + (size_t)(32u << 20)); // 8 MB  (total 40 MB)

  cvt_x<<<dim3(4096), dim3(256), 0, stream>>>(x, xb);
  cvt_T<1024, 3072><<<dim3(96, 32), dim3(256), 0, stream>>>(w_qkv, wqkvT);
  cvt_T<1024, 1024><<<dim3(32, 32), dim3(256), 0, stream>>>(w_proj, wprojT);

  gemm_bt<0><<<dim3(32 * 24), dim3(256), 0, stream>>>(xb, wqkvT, 3072,
                                                      Qb, Kb, Vb, nullptr, nullptr);
  attn<<<dim3(1024), dim3(256), 0, stream>>>(Qb, Kb, Vb, xb /* attn_out */);
  gemm_bt<1><<<dim3(32 * 8), dim3(256), 0, stream>>>(xb, wprojT, 1024,
                                                     nullptr, nullptr, nullptr, out, b_proj);
}